// Round 12
// baseline (358.580 us; speedup 1.0000x reference)
//
#include <hip/hip_runtime.h>
#include <hip/hip_bf16.h>

// ============================================================================
// SelfAttention B=4, N=4096, D=256.  Inputs fp32, OUTPUT fp32.
//
// R12: (a) merge kernel FUSED into attn epilogue: all 4 split-K blocks per
// (b,qt) write bf16 partials + lp, release-fence + atomicAdd a counter; the
// 4th arriver acquire-fences, merges (L2/L3-hot reads) and writes fp32 out.
// Counters zeroed by transpose_w (stream-ordered, re-zeroed every launch).
// (b) proj fused QKV: one block stages x ONCE, runs all 3 GEMMs (48 nt
// iters of the R11 reg-dbuf W pipeline) -> x fetched 16MB not 48MB.
// attn kt-loop unchanged from R11 (async dbuf, swizzled LDS, fixed-M).
// R11 lessons: attn LDS pipe 62% busy is the structural floor at 256-reg
// budget; VALU not binding (fast-pack was neutral).
//
// ws layout (MB): Wt@0 | Q@1 | K@10 | Vt@19 | Obf@28 (4 x 8.4) | lp@62 | cnt@63
// ============================================================================

typedef __attribute__((ext_vector_type(8))) short bf16x8;   // MFMA A/B frag (4 VGPR)
typedef __attribute__((ext_vector_type(4))) float f32x4;    // MFMA C/D frag

__device__ __forceinline__ float b2f(ushort u){
  union { uint i; float f; } v; v.i = ((uint)u) << 16; return v.f;
}
__device__ __forceinline__ ushort f2b(float f){             // round-to-nearest-even
  union { float f; uint i; } v; v.f = f;
  uint i = v.i;
  return (ushort)((i + 0x7FFFu + ((i >> 16) & 1u)) >> 16);
}
__device__ __forceinline__ uint pack2(float a, float b){
  return (uint)f2b(a) | ((uint)f2b(b) << 16);
}
__device__ __forceinline__ uint fbits(float f){
  union { float f; uint i; } v; v.f = f; return v.i;
}

// async 16B global -> LDS (DMA; LDS dest = wave-uniform base + lane*16)
__device__ __forceinline__ void gl_lds16(const ushort* g, ushort* l){
  __builtin_amdgcn_global_load_lds(
      (const __attribute__((address_space(1))) uint*)g,
      (__attribute__((address_space(3))) uint*)l, 16, 0, 0);
}

// log2(e)/sqrt(256) = 1.4426950408889634/16
#define Q_SCALE 0.0901684400555602f
#define FIXED_M 16.0f

// ---------------------------------------------------------------------------
// W transpose + fp32->bf16 + zero the merge counters.
// ---------------------------------------------------------------------------
__global__ __launch_bounds__(256) void transpose_w_kernel(
    const float* __restrict__ Wk, const float* __restrict__ Wq,
    const float* __restrict__ Wv, ushort* __restrict__ Wt,
    int* __restrict__ cnt){
  __shared__ ushort t[64][72];                 // +8 pad
  if (blockIdx.x == 0 && blockIdx.y == 0 && threadIdx.x < 128)
    cnt[threadIdx.x] = 0;                      // merge counters (128 = 4b x 32qt)
  const float* src = (blockIdx.y == 0) ? Wk : (blockIdx.y == 1) ? Wq : Wv;
  ushort* dst = Wt + blockIdx.y * 65536;
  int tile = blockIdx.x;
  int tr = tile >> 2, tc = tile & 3;           // 4x4 tiles of 64x64
  int tid = threadIdx.x;
  for (int i = tid; i < 1024; i += 256){       // 64 rows x 16 chunks of 4 floats
    int r = i >> 4, ch = i & 15;
    float4 f = *(const float4*)(src + (tr*64 + r)*256 + tc*64 + ch*4);
    uint2 u; u.x = pack2(f.x, f.y); u.y = pack2(f.z, f.w);
    *(uint2*)&t[r][ch*4] = u;
  }
  __syncthreads();
  for (int i = tid; i < 2048; i += 256){       // 64 cols x 32 row-pairs
    int c = i >> 5, r2 = (i & 31)*2;
    uint v = (uint)t[r2][c] | ((uint)t[r2+1][c] << 16);
    *(uint*)(dst + (tc*64 + c)*256 + tr*64 + r2) = v;  // coalesced 4B stores
  }
}

// ---------------------------------------------------------------------------
// Fused QKV projection: x staged ONCE per block, then 48 nt-iterations
// (3 matrices x 16 col-tiles) of the reg-dbuf W pipeline (1 barrier/iter).
// 256 blocks x 64 rows.  it = my*16+nt; my: 0=K, 1=Q(scaled), 2=V->Vt.
// ---------------------------------------------------------------------------
__global__ __launch_bounds__(256) void proj_kernel(
    const float* __restrict__ x, const ushort* __restrict__ Wt,
    const float* __restrict__ bK, const float* __restrict__ bQ,
    const float* __restrict__ bV,
    ushort* __restrict__ Ko, ushort* __restrict__ Qo, ushort* __restrict__ Vt){
  __shared__ ushort xs[64][264];      // A tile (bf16), +8 pad
  __shared__ ushort wt[2][16][264];   // B tile double buffer
  int n0 = blockIdx.x * 64;

  int tid = threadIdx.x;
  int lane = tid & 63, w = tid >> 6, quad = lane >> 4, l16 = lane & 15;

  for (int i = tid; i < 4096; i += 256){       // stage x: 64 rows x 64 f4-chunks
    int r = i >> 6, ch = i & 63;
    float4 f = *(const float4*)(x + (size_t)(n0 + r)*256 + ch*4);
    uint2 u; u.x = pack2(f.x, f.y); u.y = pack2(f.z, f.w);
    *(uint2*)&xs[r][ch*4] = u;
  }

  // per-thread W staging slots: 2 x 16B of the 8KB tile
  int seg0 = tid*2,     r0 = seg0 >> 5, c0 = seg0 & 31;
  int seg1 = tid*2 + 1, r1 = seg1 >> 5, c1 = seg1 & 31;
  {                                            // prologue: stage W(it=0) -> wt[0]
    uint4 a = *(const uint4*)(Wt + r0*256 + c0*8);
    uint4 b = *(const uint4*)(Wt + r1*256 + c1*8);
    *(uint4*)&wt[0][r0][c0*8] = a;
    *(uint4*)&wt[0][r1][c1*8] = b;
  }
  __syncthreads();

  bf16x8 afr[8];                               // wave's 16 rows, all of K=256
  #pragma unroll
  for (int ks = 0; ks < 8; ks++)
    afr[ks] = *(const bf16x8*)&xs[w*16 + l16][ks*32 + quad*8];

  for (int it = 0; it < 48; it++){             // my = it>>4, nt = it&15
    int my = it >> 4, nt = it & 15;
    int cu = it & 1;
    uint4 wa, wb;
    if (it < 47){                              // load next W tile early (hidden)
      const ushort* wn = Wt + (it+1)*4096;     // = Wt + my'*65536 + nt'*4096
      wa = *(const uint4*)(wn + r0*256 + c0*8);
      wb = *(const uint4*)(wn + r1*256 + c1*8);
    }
    f32x4 acc = {0.f, 0.f, 0.f, 0.f};
    #pragma unroll
    for (int ks = 0; ks < 8; ks++){
      bf16x8 bfr = *(const bf16x8*)&wt[cu][l16][ks*32 + quad*8];
      acc = __builtin_amdgcn_mfma_f32_16x16x32_bf16(afr[ks], bfr, acc, 0, 0, 0);
    }
    int e = nt*16 + l16;
    const float* bias = (my==0) ? bK : (my==1) ? bQ : bV;
    float bv = bias[e];
    if (my == 2){                              // V: write transposed Vt[b][e][n]
      int b  = n0 >> 12;
      int nl = (n0 & 4095) + w*16 + quad*4;    // n within batch
      ushort* vb = Vt + (size_t)b*1048576 + (size_t)e*4096 + nl;
      #pragma unroll
      for (int r = 0; r < 4; r++) vb[r] = f2b(acc[r] + bv);
    } else {
      float scale = (my==1) ? Q_SCALE : 1.0f;
      ushort* out = (my==0) ? Ko : Qo;
      #pragma unroll
      for (int r = 0; r < 4; r++){
        int row = n0 + w*16 + quad*4 + r;      // C layout: row=quad*4+r, col=l16
        out[(size_t)row*256 + e] = f2b((acc[r] + bv) * scale);
      }
    }
    if (it < 47){                              // commit next tile to wt[cu^1]
      *(uint4*)&wt[cu^1][r0][c0*8] = wa;
      *(uint4*)&wt[cu^1][r1][c1*8] = wb;
    }
    __syncthreads();
  }
}

// ---------------------------------------------------------------------------
// Flash attention, split-K x4, 2 q-sets/wave, fixed-M softmax, async dbuf,
// FUSED MERGE: every block writes a bf16 partial (scale 2^-16) + lp, then
// release-fence + atomicAdd(cnt[b*32+qt]); the 4th arriver merges all 4
// partials and writes the final fp32 rows of d_out.
// ---------------------------------------------------------------------------
__global__ __launch_bounds__(256, 2) void attn_kernel(
    const ushort* __restrict__ Q, const ushort* __restrict__ K,
    const ushort* __restrict__ Vt,
    float* __restrict__ out, ushort* __restrict__ Obf,
    float* __restrict__ lp, int* __restrict__ cnt){
  __shared__ ushort Kbuf[2][8192];   // 32 keys x 256 d, unpadded+swizzled
  __shared__ ushort Vbuf[2][8192];   // 256 d x 32 keys, unpadded+swizzled
  __shared__ ushort Ps[128][40];     // P round-trip, wave-private rows
  __shared__ int s_last;

  int bx   = blockIdx.x;
  int bh   = bx & 15;
  int b    = bh >> 2;                       // batch 0..3
  int half = bh & 3;                        // k-quarter 0..3
  int qt   = bx >> 4;                       // q-tile 0..31 (128 q each)
  int tid = threadIdx.x, lane = tid & 63, w = tid >> 6;
  int quad = lane >> 4, l16 = lane & 15;

  const ushort* Qb = Q  + (size_t)(b*4096 + qt*128)*256;
  const ushort* Kb = K  + (size_t)b*4096*256;
  const ushort* Vb = Vt + (size_t)b*256*4096;

  // ---- staging lane->global offset precompute (swizzled) -----------------
  int kOff[4], vOff[4];
  #pragma unroll
  for (int i = 0; i < 4; i++){
    int off16 = (w*4 + i)*64 + lane;         // 16B unit within 16KB tile
    int krow = off16 >> 5, ks_ = off16 & 31;
    int g    = ks_ ^ (krow & 7);             // K swizzle: chunk stored at slot
    kOff[i]  = krow*256 + g*8;               // ushort offset in K global tile
    int sr = off16 >> 3, sl = off16 & 7;     // V: 128B superrow, 16B slot
    int xv = sl ^ (sr & 7);
    int d  = sr*2 + ((xv >> 2) & 1), c = xv & 3;
    vOff[i] = d*4096 + c*8;                  // ushort offset (Vt row stride 4096)
  }
  // compute-side swizzled read offsets
  int m7 = l16 & 7;
  int kslot[8];
  #pragma unroll
  for (int ks = 0; ks < 8; ks++) kslot[ks] = ((ks*4 + quad) ^ m7) * 8;
  int vlane = (((l16 >> 1)*8) + (((l16 & 1)*4 + quad) ^ (l16 >> 1))) * 8;

  bf16x8 qf[2][8];                 // A-frags, 2 sets: rows w*32+s*16+l16
  #pragma unroll
  for (int s = 0; s < 2; s++)
    #pragma unroll
    for (int ks = 0; ks < 8; ks++)
      qf[s][ks] = *(const bf16x8*)(Qb + (size_t)(w*32 + s*16 + l16)*256 + ks*32 + quad*8);

  f32x4 of[2][16];                 // O accumulators
  #pragma unroll
  for (int s = 0; s < 2; s++)
    #pragma unroll
    for (int dt = 0; dt < 16; dt++) of[s][dt] = (f32x4){0.f, 0.f, 0.f, 0.f};
  float l_i[2][4];                 // per-LANE partial sums (2 cols each)
  #pragma unroll
  for (int s = 0; s < 2; s++)
    #pragma unroll
    for (int r = 0; r < 4; r++) l_i[s][r] = 0.f;

  int kt0 = half * 32, kt1 = kt0 + 32;

  // ---- prologue: stage kt0 into buf 0, drain ----------------------------
  #pragma unroll
  for (int i = 0; i < 4; i++){
    gl_lds16(Kb + (size_t)kt0*8192 + kOff[i], &Kbuf[0][(w*4 + i)*512]);
    gl_lds16(Vb + (size_t)kt0*32   + vOff[i], &Vbuf[0][(w*4 + i)*512]);
  }
  __syncthreads();

  int cur = 0;
  for (int kt = kt0; kt < kt1; kt++){
    int nxt = cur ^ 1;
    if (kt + 1 < kt1){                       // async prefetch kt+1 -> buf[nxt]
      #pragma unroll
      for (int i = 0; i < 4; i++){
        gl_lds16(Kb + (size_t)(kt+1)*8192 + kOff[i], &Kbuf[nxt][(w*4 + i)*512]);
        gl_lds16(Vb + (size_t)(kt+1)*32   + vOff[i], &Vbuf[nxt][(w*4 + i)*512]);
      }
    }
    const ushort* Kc = &Kbuf[cur][0];
    const ushort* Vc = &Vbuf[cur][0];

    // ---- S = Qhat @ K^T : each Ks B-frag feeds both q-sets ---------------
    f32x4 sf[2][2];                          // [set][nt]
    #pragma unroll
    for (int s = 0; s < 2; s++)
      #pragma unroll
      for (int nt = 0; nt < 2; nt++) sf[s][nt] = (f32x4){0.f, 0.f, 0.f, 0.f};
    #pragma unroll
    for (int nt = 0; nt < 2; nt++){
      const ushort* Kr = Kc + nt*4096 + l16*256;
      #pragma unroll
      for (int ks = 0; ks < 8; ks++){
        bf16x8 bfr = *(const bf16x8*)(Kr + kslot[ks]);
        sf[0][nt] = __builtin_amdgcn_mfma_f32_16x16x32_bf16(qf[0][ks], bfr, sf[0][nt], 0,0,0);
        sf[1][nt] = __builtin_amdgcn_mfma_f32_16x16x32_bf16(qf[1][ks], bfr, sf[1][nt], 0,0,0);
      }
    }

    // ---- fixed-M softmax: p = exp2(s-16); fast bf16 pack (round-half-up) -
    #pragma unroll
    for (int s = 0; s < 2; s++){
      #pragma unroll
      for (int r = 0; r < 4; r++){
        float p0 = exp2f(sf[s][0][r] - FIXED_M);
        float p1 = exp2f(sf[s][1][r] - FIXED_M);
        l_i[s][r] += p0 + p1;
        uint pb = __builtin_amdgcn_perm(fbits(p1) + 0x8000u,
                                        fbits(p0) + 0x8000u, 0x07060302u);
        ushort* prow = &Ps[w*32 + s*16 + quad*4 + r][0];
        prow[l16]      = (ushort)pb;
        prow[16 + l16] = (ushort)(pb >> 16);
      }
    }
    // wave-private LDS round-trip: same-wave ds ordering via lgkmcnt.

    // ---- PV: each Vs B-frag feeds both q-sets ----------------------------
    bf16x8 pf0 = *(const bf16x8*)&Ps[w*32 +      l16][quad*8];
    bf16x8 pf1 = *(const bf16x8*)&Ps[w*32 + 16 + l16][quad*8];
    #pragma unroll
    for (int dt = 0; dt < 16; dt++){
      bf16x8 vf = *(const bf16x8*)(Vc + dt*512 + vlane);  // B[k][n]=V[key][d]
      of[0][dt] = __builtin_amdgcn_mfma_f32_16x16x32_bf16(pf0, vf, of[0][dt], 0, 0, 0);
      of[1][dt] = __builtin_amdgcn_mfma_f32_16x16x32_bf16(pf1, vf, of[1][dt], 0, 0, 0);
    }

    __syncthreads();   // drains prefetch (vmcnt0) + fences buffer swap
    cur = nxt;
  }

  // ---- one l reduction for the whole kernel ------------------------------
  #pragma unroll
  for (int s = 0; s < 2; s++)
    #pragma unroll
    for (int r = 0; r < 4; r++){
      float rs = l_i[s][r];
      #pragma unroll
      for (int msk = 1; msk < 16; msk <<= 1) rs += __shfl_xor(rs, msk, 16);
      l_i[s][r] = rs;
    }

  // ---- write bf16 partial + l --------------------------------------------
  ushort* Oh = Obf + (size_t)half*16384*256;
  #pragma unroll
  for (int s = 0; s < 2; s++){
    int gq0 = b*4096 + qt*128 + w*32 + s*16 + quad*4;  // global q row, r=0
    if (l16 == 0){
      #pragma unroll
      for (int r = 0; r < 4; r++)
        lp[(size_t)half*16384 + gq0 + r] = l_i[s][r];
    }
    #pragma unroll
    for (int dt = 0; dt < 16; dt++)
      #pragma unroll
      for (int r = 0; r < 4; r++)
        Oh[(size_t)(gq0 + r)*256 + dt*16 + l16] = f2b(of[s][dt][r]);
  }

  // ---- last-arriver merges the 4 partials --------------------------------
  __threadfence();                             // release: partial visible
  __syncthreads();
  if (tid == 0) s_last = (atomicAdd(&cnt[b*32 + qt], 1) == 3);
  __syncthreads();
  if (s_last){
    __threadfence();                           // acquire: others' partials
    int base = b*4096 + qt*128;                // 128 rows to finalize
    for (int i = tid; i < 8192; i += 256){     // 128 rows x 64 col-chunks of 4
      int row = i >> 6, c = (i & 63)*4;
      float den = lp[base + row] + lp[16384 + base + row]
                + lp[2*16384 + base + row] + lp[3*16384 + base + row];
      float rden = 1.0f / den;
      size_t idx = (size_t)(base + row)*256 + c;
      float4 acc = {0.f, 0.f, 0.f, 0.f};
      #pragma unroll
      for (int h = 0; h < 4; h++){
        ushort4 oh = *(const ushort4*)&Obf[(size_t)h*16384*256 + idx];
        acc.x += b2f(oh.x); acc.y += b2f(oh.y);
        acc.z += b2f(oh.z); acc.w += b2f(oh.w);
      }
      acc.x *= rden; acc.y *= rden; acc.z *= rden; acc.w *= rden;
      *(float4*)&out[idx] = acc;
    }
  }
}

// ---------------------------------------------------------------------------
extern "C" void kernel_launch(void* const* d_in, const int* in_sizes, int n_in,
                              void* d_out, int out_size, void* d_ws, size_t ws_size,
                              hipStream_t stream){
  const float* x  = (const float*)d_in[0];
  const float* Wk = (const float*)d_in[1];
  const float* bk = (const float*)d_in[2];
  const float* Wq = (const float*)d_in[3];
  const float* bq = (const float*)d_in[4];
  const float* Wv = (const float*)d_in[5];
  const float* bv = (const float*)d_in[6];

  char* ws = (char*)d_ws;
  ushort* Wt  = (ushort*)(ws);                       // 3 x 256 x 256 bf16
  ushort* Qb  = (ushort*)(ws + (size_t)1*(1u<<20));  // 16384 x 256 bf16
  ushort* Kb  = (ushort*)(ws + (size_t)10*(1u<<20));
  ushort* Vtb = (ushort*)(ws + (size_t)19*(1u<<20)); // 4 x 256 x 4096 bf16
  ushort* Obf = (ushort*)(ws + (size_t)28*(1u<<20)); // 4 x 16384 x 256 bf16
  float*  lp  = (float*)(ws + (size_t)62*(1u<<20));  // [4][16384] fp32
  int*    cnt = (int*)(ws + (size_t)63*(1u<<20));    // 128 merge counters

  hipLaunchKernelGGL(transpose_w_kernel, dim3(16, 3), dim3(256), 0, stream,
                     Wk, Wq, Wv, Wt, cnt);
  hipLaunchKernelGGL(proj_kernel, dim3(256), dim3(256), 0, stream,
                     x, Wt, bk, bq, bv, Kb, Qb, Vtb);
  hipLaunchKernelGGL(attn_kernel, dim3(512), dim3(256), 0, stream,
                     Qb, Kb, Vtb, (float*)d_out, Obf, lp, cnt);
}